// Round 11
// baseline (193.201 us; speedup 1.0000x reference)
//
#include <hip/hip_runtime.h>
#include <hip/hip_bf16.h>

#define SEQLEN 2048
#define DMODEL 1024
#define INNER  2048
#define DSTATE 16
#define DTRANK 64
#define NPROJ  96    // valid rows of W_x; padded to 128
#define NPAD   128
#define CHUNK  16
#define NCH    128   // SEQLEN / CHUNK
#define KSPLIT 16    // x-proj split-K ways

typedef __attribute__((ext_vector_type(8))) short bf16x8;
typedef __attribute__((ext_vector_type(4))) float f32x4;

__device__ __forceinline__ float softplusf(float x) {
    return (x > 20.f) ? x : log1pf(__expf(x));
}
__device__ __forceinline__ unsigned short f2bf(float x) {
    unsigned u = __float_as_uint(x);
    return (unsigned short)((u + 0x7FFF + ((u >> 16) & 1)) >> 16);
}
__device__ __forceinline__ float bf2f(unsigned short x) {
    return __uint_as_float((unsigned)x << 16);
}
__device__ __forceinline__ void gload_lds16(const void* g, void* l) {
    __builtin_amdgcn_global_load_lds(
        (__attribute__((address_space(1))) const unsigned int*)g,
        (__attribute__((address_space(3))) unsigned int*)l,
        16, 0, 0);
}
__device__ __forceinline__ void cvt8(const float* __restrict__ in,
                                     unsigned short* __restrict__ out, int i) {
    float4 a = ((const float4*)in)[2 * i];
    float4 b = ((const float4*)in)[2 * i + 1];
    uint4 v;
    v.x = f2bf(a.x) | ((unsigned)f2bf(a.y) << 16);
    v.y = f2bf(a.z) | ((unsigned)f2bf(a.w) << 16);
    v.z = f2bf(b.x) | ((unsigned)f2bf(b.y) << 16);
    v.w = f2bf(b.z) | ((unsigned)f2bf(b.w) << 16);
    ((uint4*)out)[i] = v;
}

// One-shot conversion of all bf16 operands.
// Segments (8-elem units): hidden 262144 | W_in 524288 | W_out 262144 |
// W_dt 16384 | W_x padded 96->128 rows 32768.  Total 1097728 units.
__global__ __launch_bounds__(256)
void cvt_all(const float* __restrict__ hidden, const float* __restrict__ W_in,
             const float* __restrict__ W_out, const float* __restrict__ W_dt,
             const float* __restrict__ W_x,
             unsigned short* __restrict__ hid_b, unsigned short* __restrict__ Win_b,
             unsigned short* __restrict__ Wout_b, unsigned short* __restrict__ Wdt_b,
             unsigned short* __restrict__ Wx_b)
{
    int i = blockIdx.x * 256 + threadIdx.x;
    if (i < 262144) { cvt8(hidden, hid_b, i); return; }
    i -= 262144;
    if (i < 524288) { cvt8(W_in, Win_b, i); return; }
    i -= 524288;
    if (i < 262144) { cvt8(W_out, Wout_b, i); return; }
    i -= 262144;
    if (i < 16384)  { cvt8(W_dt, Wdt_b, i); return; }
    i -= 16384;
    if (i < 32768) {
        int row = i >> 8;              // 256 units per 2048-wide row
        if (row < NPROJ) cvt8(W_x, Wx_b, i);
        else ((uint4*)Wx_b)[i] = make_uint4(0, 0, 0, 0);
    }
}

// C = A @ B^T, bf16 MFMA, fp32 accum.  BK=64, involution LDS swizzle
// (linear gload_lds dest + chunk^(row&7) pre-swizzled global source + XOR'd
// ds_read), bijective XCD swizzle on (bx,by).  Requires gridDim.x*y % 8 == 0,
// K/kspan % 64 == 0, M % BM == 0, N % BN == 0.
// 256 thr = 4 waves 2x2; wave tile (BM/2)x(BN/2); 16x16x32 MFMA.
// EPI 0: fp32 C (+ blockIdx.z*zCstride for split-K partials).  EPI 1: bf16 C.
template<int BM, int BN, int EPI>
__global__ __launch_bounds__(256)
void gemm_bf16(const unsigned short* __restrict__ A, const int lda,
               const unsigned short* __restrict__ B, const int ldb,
               void* __restrict__ Cv, const int ldc, const long long zCstride,
               const int K, const int kspan)
{
    constexpr int FM = BM / 32;
    constexpr int FN = BN / 32;
    __shared__ alignas(16) short As[BM * 64];
    __shared__ alignas(16) short Bs[BN * 64];

    const int tid  = threadIdx.x;
    const int wave = tid >> 6;
    const int lane = tid & 63;

    // XCD-aware bijective swizzle of the flattened (bx,by) index
    int bid = blockIdx.y * gridDim.x + blockIdx.x;
    const int q = (gridDim.x * gridDim.y) >> 3;
    bid = (bid & 7) * q + (bid >> 3);
    const int bx = bid % gridDim.x;
    const int by = bid / gridDim.x;

    const long long row0 = (long long)by * BM;
    const long long col0 = (long long)bx * BN;
    const int wm = (wave >> 1) * (BM / 2);
    const int wn = (wave & 1) * (BN / 2);
    const int kstart = blockIdx.z * kspan;
    const int kend   = min(K, kstart + kspan);

    f32x4 acc[FM][FN] = {};

    // staging: thread t -> LDS row t/8 (+32 per pass), chunk t&7 (linear,
    // byte addr = t*16), fetching GLOBAL chunk (t&7)^(row&7)
    const int srow   = tid >> 3;
    const int schunk = (tid & 7) ^ (srow & 7);
    const unsigned short* gA = A + (row0 + srow) * lda + schunk * 8;
    const unsigned short* gB = B + (col0 + srow) * ldb + schunk * 8;
    short* lA = &As[srow * 64 + (tid & 7) * 8];
    short* lB = &Bs[srow * 64 + (tid & 7) * 8];

    const int fr = lane & 15;
    const int hi = lane >> 4;
    const int rb = fr & 7;            // row&7 of every fragment row this lane reads

    for (int kt = kstart; kt < kend; kt += 64) {
#pragma unroll
        for (int r = 0; r < BM; r += 32)
            gload_lds16(gA + (long long)r * lda + kt, lA + r * 64);
#pragma unroll
        for (int r = 0; r < BN; r += 32)
            gload_lds16(gB + (long long)r * ldb + kt, lB + r * 64);
        __syncthreads();

#pragma unroll
        for (int half = 0; half < 2; ++half) {
            const int kc = (((half << 2) + hi) ^ rb) * 8;   // swizzled 16B chunk
            bf16x8 af[FM], bfr[FN];
#pragma unroll
            for (int mi = 0; mi < FM; ++mi)
                af[mi] = *(const bf16x8*)&As[(wm + mi * 16 + fr) * 64 + kc];
#pragma unroll
            for (int ni = 0; ni < FN; ++ni)
                bfr[ni] = *(const bf16x8*)&Bs[(wn + ni * 16 + fr) * 64 + kc];
#pragma unroll
            for (int mi = 0; mi < FM; ++mi)
#pragma unroll
                for (int ni = 0; ni < FN; ++ni)
                    acc[mi][ni] = __builtin_amdgcn_mfma_f32_16x16x32_bf16(
                        af[mi], bfr[ni], acc[mi][ni], 0, 0, 0);
        }
        __syncthreads();
    }

    const int cr = hi * 4;            // C/D: col=lane&15, row=(lane>>4)*4+reg
#pragma unroll
    for (int mi = 0; mi < FM; ++mi)
#pragma unroll
        for (int ni = 0; ni < FN; ++ni) {
            long long rbase = row0 + wm + mi * 16 + cr;
            long long col   = col0 + wn + ni * 16 + fr;
#pragma unroll
            for (int r = 0; r < 4; ++r) {
                long long idx = (rbase + r) * ldc + col;
                if (EPI == 0) {
                    ((float*)Cv)[(long long)blockIdx.z * zCstride + idx] = acc[mi][ni][r];
                } else {
                    ((unsigned short*)Cv)[idx] = f2bf(acc[mi][ni][r]);
                }
            }
        }
}

// Fused conv+silu+x-proj GEMM: part[z] = u_patch @ Wx^T where
// u = silu(depthwise_conv(xz_proj) + cb) is computed IN the A-staging from
// xz_b and also written to u_b (each (l,d) exactly once: z partitions the
// channel/K dim, by partitions rows).  BM=BN=128, BK=64, kspan=128,
// grid (1,16,KSPLIT); same swizzles/epilogue as gemm_bf16 EPI=0.
__global__ __launch_bounds__(256)
void xproj_fused(const unsigned short* __restrict__ xz_b,
                 const float* __restrict__ cw, const float* __restrict__ cb,
                 const unsigned short* __restrict__ Wx_b,
                 unsigned short* __restrict__ u_b, float* __restrict__ Cv)
{
    __shared__ alignas(16) short As[128 * 64];
    __shared__ alignas(16) short Bs[128 * 64];

    const int tid  = threadIdx.x;
    const int wave = tid >> 6;
    const int lane = tid & 63;

    int bid = blockIdx.y;                  // gridDim.x == 1, 16 blocks in y
    bid = (bid & 7) * 2 + (bid >> 3);      // bijective XCD swizzle (q=2)
    const long long row0 = (long long)bid * 128;

    const int wm = (wave >> 1) * 64;
    const int wn = (wave & 1) * 64;
    const int kstart = blockIdx.z * (INNER / KSPLIT);   // 128-channel span

    f32x4 acc[2][2] = {};

    const int srow   = tid >> 3;
    const int gchunk = (tid & 7) ^ (srow & 7);
    short* lA = &As[srow * 64 + (tid & 7) * 8];
    short* lB = &Bs[srow * 64 + (tid & 7) * 8];
    const unsigned short* gB = Wx_b + srow * INNER + gchunk * 8;

    const int fr = lane & 15;
    const int hi = lane >> 4;
    const int rb = fr & 7;

    for (int kt = kstart; kt < kstart + 128; kt += 64) {
        const int d = kt + gchunk * 8;     // my 8 channels this K-tile
        float4 wv[8];
#pragma unroll
        for (int k = 0; k < 8; ++k) wv[k] = ((const float4*)cw)[d + k];
        float bias8[8];
        {
            float4 c0 = ((const float4*)cb)[d >> 2];
            float4 c1 = ((const float4*)cb)[(d >> 2) + 1];
            bias8[0] = c0.x; bias8[1] = c0.y; bias8[2] = c0.z; bias8[3] = c0.w;
            bias8[4] = c1.x; bias8[5] = c1.y; bias8[6] = c1.z; bias8[7] = c1.w;
        }
#pragma unroll
        for (int r = 0; r < 128; r += 32) {
            const long long l = row0 + srow + r;
            float a[8];
#pragma unroll
            for (int k = 0; k < 8; ++k) a[k] = bias8[k];
#pragma unroll
            for (int j = 0; j < 4; ++j) {
                long long ls = l - 3 + j;
                if (ls >= 0) {
                    bf16x8 x = *(const bf16x8*)&xz_b[ls * 4096 + d];
#pragma unroll
                    for (int k = 0; k < 8; ++k)
                        a[k] = fmaf(((const float*)&wv[k])[j],
                                    bf2f((unsigned short)x[k]), a[k]);
                }
            }
            float s8[8];
#pragma unroll
            for (int k = 0; k < 8; ++k) s8[k] = a[k] / (1.f + __expf(-a[k]));
            uint4 p;
            p.x = f2bf(s8[0]) | ((unsigned)f2bf(s8[1]) << 16);
            p.y = f2bf(s8[2]) | ((unsigned)f2bf(s8[3]) << 16);
            p.z = f2bf(s8[4]) | ((unsigned)f2bf(s8[5]) << 16);
            p.w = f2bf(s8[6]) | ((unsigned)f2bf(s8[7]) << 16);
            *(uint4*)(lA + r * 64) = p;                 // swizzled LDS slot
            *(uint4*)&u_b[l * INNER + d] = p;           // global u (once)
        }
#pragma unroll
        for (int r = 0; r < 128; r += 32)
            gload_lds16(gB + (long long)r * INNER + kt, lB + r * 64);
        __syncthreads();

#pragma unroll
        for (int half = 0; half < 2; ++half) {
            const int kc = (((half << 2) + hi) ^ rb) * 8;
            bf16x8 af[2], bfr[2];
#pragma unroll
            for (int mi = 0; mi < 2; ++mi)
                af[mi] = *(const bf16x8*)&As[(wm + mi * 16 + fr) * 64 + kc];
#pragma unroll
            for (int ni = 0; ni < 2; ++ni)
                bfr[ni] = *(const bf16x8*)&Bs[(wn + ni * 16 + fr) * 64 + kc];
#pragma unroll
            for (int mi = 0; mi < 2; ++mi)
#pragma unroll
                for (int ni = 0; ni < 2; ++ni)
                    acc[mi][ni] = __builtin_amdgcn_mfma_f32_16x16x32_bf16(
                        af[mi], bfr[ni], acc[mi][ni], 0, 0, 0);
        }
        __syncthreads();
    }

    const int cr = hi * 4;
#pragma unroll
    for (int mi = 0; mi < 2; ++mi)
#pragma unroll
        for (int ni = 0; ni < 2; ++ni) {
            long long rbase = row0 + wm + mi * 16 + cr;
            long long col   = wn + ni * 16 + fr;
#pragma unroll
            for (int r = 0; r < 4; ++r)
                Cv[(long long)blockIdx.z * (SEQLEN * NPAD) +
                   (rbase + r) * NPAD + col] = acc[mi][ni][r];
        }
}

// out[i] = p0[i] + p1[i]  (split-K=2 combine), float4 vectorized
__global__ __launch_bounds__(256)
void reduce_out(const float* __restrict__ part, float* __restrict__ out)
{
    int i = blockIdx.x * 256 + threadIdx.x;   // i < SEQLEN*DMODEL/4
    float4 a = ((const float4*)part)[i];
    float4 b = ((const float4*)part)[i + SEQLEN * DMODEL / 4];
    a.x += b.x; a.y += b.y; a.z += b.z; a.w += b.w;
    ((float4*)out)[i] = a;
}

// Fused split-K reduce + delta GEMM.  128 blocks x 16 seq-rows each:
// (a) projt[l, 0:128] = sum_z part[z][l][:]  (same per-element z-order as the
//     old reduce_part -> bit-identical),
// (b) A-tile = f2bf(projt[l, 0:64]) parked in LDS (same values old projt_b had),
// (c) delta[l, :] = f2bf(softplus(A @ W_dt^T + dt_bias)) via the round-10
//     bit-verified MFMA fragment path (B read from L2-resident Wdt_b).
// Register-thin: no scan state in this kernel.
__global__ __launch_bounds__(256)
void reduce_delta(const float* __restrict__ part,
                  const unsigned short* __restrict__ Wdt_b,
                  const float* __restrict__ dt_bias,
                  float* __restrict__ projt, unsigned short* __restrict__ dlt_b)
{
    __shared__ unsigned short albs[16 * 64];   // bf16 A tile (2 KB)
    const int tid = threadIdx.x;
    const int l0  = blockIdx.x * 16;

    // --- split-K reduce: 16 rows x 128 cols, 8 consecutive cols per thread ---
    const int rrow = tid >> 4;          // 0..15
    const int rcol = (tid & 15) * 8;    // 0,8,...,120
    const long long ibase = (long long)(l0 + rrow) * NPAD + rcol;
    float4 s0 = make_float4(0.f, 0.f, 0.f, 0.f);
    float4 s1 = make_float4(0.f, 0.f, 0.f, 0.f);
#pragma unroll
    for (int z = 0; z < KSPLIT; ++z) {
        const float* p = part + (long long)z * SEQLEN * NPAD + ibase;
        float4 a = ((const float4*)p)[0];
        float4 b = ((const float4*)p)[1];
        s0.x += a.x; s0.y += a.y; s0.z += a.z; s0.w += a.w;
        s1.x += b.x; s1.y += b.y; s1.z += b.z; s1.w += b.w;
    }
    ((float4*)&projt[ibase])[0] = s0;
    ((float4*)&projt[ibase])[1] = s1;
    if (rcol < 64) {
        uint4 p;
        p.x = f2bf(s0.x) | ((unsigned)f2bf(s0.y) << 16);
        p.y = f2bf(s0.z) | ((unsigned)f2bf(s0.w) << 16);
        p.z = f2bf(s1.x) | ((unsigned)f2bf(s1.y) << 16);
        p.w = f2bf(s1.z) | ((unsigned)f2bf(s1.w) << 16);
        *(uint4*)&albs[rrow * 64 + rcol] = p;
    }
    __syncthreads();

    // --- delta GEMM: M=16, N=2048, K=64; 4 waves x 4 N-frags x 8 d0-iters ---
    const int wv   = tid >> 6;
    const int lane = tid & 63;
    const int fr   = lane & 15;
    const int hi   = lane >> 4;

    bf16x8 a0 = *(const bf16x8*)&albs[fr * 64 + hi * 8];
    bf16x8 a1 = *(const bf16x8*)&albs[fr * 64 + 32 + hi * 8];

    for (int d0 = 0; d0 < INNER; d0 += 256) {
        f32x4 acc[4] = {};
#pragma unroll
        for (int ni = 0; ni < 4; ++ni) {
            const int d = d0 + wv * 64 + ni * 16 + fr;
            bf16x8 b0 = *(const bf16x8*)&Wdt_b[d * DTRANK + hi * 8];
            acc[ni] = __builtin_amdgcn_mfma_f32_16x16x32_bf16(a0, b0, acc[ni], 0, 0, 0);
            bf16x8 b1 = *(const bf16x8*)&Wdt_b[d * DTRANK + 32 + hi * 8];
            acc[ni] = __builtin_amdgcn_mfma_f32_16x16x32_bf16(a1, b1, acc[ni], 0, 0, 0);
        }
#pragma unroll
        for (int ni = 0; ni < 4; ++ni) {
            const int dcol = d0 + wv * 64 + ni * 16 + fr;
            const float bias = dt_bias[dcol];
#pragma unroll
            for (int r = 0; r < 4; ++r)
                dlt_b[(long long)(l0 + hi * 4 + r) * INNER + dcol] =
                    f2bf(softplusf(acc[ni][r] + bias));
        }
    }
}

// Phase 1: local chunk scans (h0=0) -> bf16 chunk-final states + delta sums
__global__ __launch_bounds__(256)
void scan_phase1(const unsigned short* __restrict__ delta_bf,
                 const unsigned short* __restrict__ u_b,
                 const float* __restrict__ projt, const float* __restrict__ A_log,
                 unsigned short* __restrict__ Slocb, float* __restrict__ sumd)
{
    __shared__ float Bsh[CHUNK][16];
    const int d  = blockIdx.x * 256 + threadIdx.x;
    const int c  = blockIdx.y;
    const int l0 = c * CHUNK;
    for (int i = threadIdx.x; i < CHUNK * 16; i += 256) {
        int l = i >> 4, j = i & 15;
        Bsh[l][j] = projt[(l0 + l) * NPAD + DTRANK + j];
    }
    __syncthreads();

    float A2[DSTATE];
#pragma unroll
    for (int n = 0; n < DSTATE; ++n)
        A2[n] = -__expf(A_log[d * DSTATE + n]) * 1.4426950408889634f;

    float dl[CHUNK], du[CHUNK];
#pragma unroll
    for (int t = 0; t < CHUNK; ++t) {
        int l = l0 + t;
        float dv = bf2f(delta_bf[l * INNER + d]);
        dl[t] = dv;
        du[t] = dv * bf2f(u_b[l * INNER + d]);
    }

    float h[DSTATE];
#pragma unroll
    for (int n = 0; n < DSTATE; ++n) h[n] = 0.f;
    float sd = 0.f;

#pragma unroll
    for (int t = 0; t < CHUNK; ++t) {
        sd += dl[t];
#pragma unroll
        for (int n = 0; n < DSTATE; ++n) {
            float dA = exp2f(dl[t] * A2[n]);
            h[n] = fmaf(dA, h[n], du[t] * Bsh[t][n]);
        }
    }
    uint4 p0, p1;
    p0.x = f2bf(h[0])  | ((unsigned)f2bf(h[1])  << 16);
    p0.y = f2bf(h[2])  | ((unsigned)f2bf(h[3])  << 16);
    p0.z = f2bf(h[4])  | ((unsigned)f2bf(h[5])  << 16);
    p0.w = f2bf(h[6])  | ((unsigned)f2bf(h[7])  << 16);
    p1.x = f2bf(h[8])  | ((unsigned)f2bf(h[9])  << 16);
    p1.y = f2bf(h[10]) | ((unsigned)f2bf(h[11]) << 16);
    p1.z = f2bf(h[12]) | ((unsigned)f2bf(h[13]) << 16);
    p1.w = f2bf(h[14]) | ((unsigned)f2bf(h[15]) << 16);
    uint4* dst = (uint4*)&Slocb[(long long)(c * INNER + d) * DSTATE];
    dst[0] = p0; dst[1] = p1;
    sumd[c * INNER + d] = sd;
}

// Phase 2 (in-place, bf16 state): S[c] chunk-final -> state at chunk start.
// 64-thread blocks x 512 -> spread over all CUs.
__global__ __launch_bounds__(64)
void scan_phase2(unsigned short* __restrict__ S, const float* __restrict__ sumd,
                 const float* __restrict__ A_log)
{
    int i = blockIdx.x * 64 + threadIdx.x;   // i < INNER*DSTATE
    int d = i >> 4;
    float A2 = -__expf(A_log[i]) * 1.4426950408889634f;
    float H = 0.f;
#pragma unroll
    for (int c = 0; c < NCH; ++c) {
        float s = bf2f(S[c * (INNER * DSTATE) + i]);
        float P = exp2f(A2 * sumd[c * INNER + d]);
        S[c * (INNER * DSTATE) + i] = f2bf(H);
        H = fmaf(P, H, s);
    }
}

// Phase 3: re-scan from bf16 Hinit; y = (h.C + D*u) * silu(gate) -> bf16 y_b
__global__ __launch_bounds__(256)
void scan_phase3(const unsigned short* __restrict__ delta_bf,
                 const unsigned short* __restrict__ u_b,
                 const float* __restrict__ projt, const float* __restrict__ A_log,
                 const unsigned short* __restrict__ Hinit,
                 const unsigned short* __restrict__ xz_b,
                 const float* __restrict__ D_skip, unsigned short* __restrict__ ybf)
{
    __shared__ float BC[CHUNK][32];
    const int d  = blockIdx.x * 256 + threadIdx.x;
    const int c  = blockIdx.y;
    const int l0 = c * CHUNK;
    for (int i = threadIdx.x; i < CHUNK * 32; i += 256) {
        int l = i >> 5, j = i & 31;
        BC[l][j] = projt[(l0 + l) * NPAD + DTRANK + j];
    }
    __syncthreads();

    float A2[DSTATE];
#pragma unroll
    for (int n = 0; n < DSTATE; ++n)
        A2[n] = -__expf(A_log[d * DSTATE + n]) * 1.4426950408889634f;

    float dl[CHUNK], uv[CHUNK];
#pragma unroll
    for (int t = 0; t < CHUNK; ++t) {
        int l = l0 + t;
        dl[t] = bf2f(delta_bf[l * INNER + d]);
        uv[t] = bf2f(u_b[l * INNER + d]);
    }

    float h[DSTATE];
    {
        const uint4* hp = (const uint4*)&Hinit[(long long)(c * INNER + d) * DSTATE];
        uint4 p0 = hp[0], p1 = hp[1];
        h[0]  = bf2f((unsigned short)(p0.x & 0xffff)); h[1]  = bf2f((unsigned short)(p0.x >> 16));
        h[2]  = bf2f((unsigned short)(p0.y & 0xffff)); h[3]  = bf2f((unsigned short)(p0.y >> 16));
        h[4]  = bf2f((unsigned short)(p0.z & 0xffff)); h[5]  = bf2f((unsigned short)(p0.z >> 16));
        h[6]  = bf2f((unsigned short)(p0.w & 0xffff)); h[7]  = bf2f((unsigned short)(p0.w >> 16));
        h[8]  = bf2f((unsigned short)(p1.x & 0xffff)); h[9]  = bf2f((unsigned short)(p1.x >> 16));
        h[10] = bf2f((unsigned short)(p1.y & 0xffff)); h[11] = bf2f((unsigned short)(p1.y >> 16));
        h[12] = bf2f((unsigned short)(p1.z & 0xffff)); h[13] = bf2f((unsigned short)(p1.z >> 16));
        h[14] = bf2f((unsigned short)(p1.w & 0xffff)); h[15] = bf2f((unsigned short)(p1.w >> 16));
    }
    const float Dd = D_skip[d];

#pragma unroll
    for (int t = 0; t < CHUNK; ++t) {
        int l = l0 + t;
        float du = dl[t] * uv[t];
        float y = 0.f;
#pragma unroll
        for (int n = 0; n < DSTATE; ++n) {
            float dA = exp2f(dl[t] * A2[n]);
            h[n] = fmaf(dA, h[n], du * BC[t][n]);
            y = fmaf(h[n], BC[t][16 + n], y);
        }
        float yv = fmaf(Dd, uv[t], y);
        float g = bf2f(xz_b[(long long)l * 4096 + 2048 + d]);
        float sg = g / (1.f + __expf(-g));
        ybf[l * INNER + d] = f2bf(yv * sg);
    }
}

extern "C" void kernel_launch(void* const* d_in, const int* in_sizes, int n_in,
                              void* d_out, int out_size, void* d_ws, size_t ws_size,
                              hipStream_t stream)
{
    const float* hidden  = (const float*)d_in[0];
    const float* W_in    = (const float*)d_in[1];
    const float* conv_w  = (const float*)d_in[2];
    const float* conv_b  = (const float*)d_in[3];
    const float* W_x     = (const float*)d_in[4];
    const float* W_dt    = (const float*)d_in[5];
    const float* dt_bias = (const float*)d_in[6];
    const float* A_log   = (const float*)d_in[7];
    const float* D_skip  = (const float*)d_in[8];
    const float* W_out   = (const float*)d_in[9];
    float* out = (float*)d_out;

    // workspace layout, 66.3 MB total (proven ceiling 82.6 MB, round 4).
    // Triple-aliased slot [25165824, 41943040): part16 (xproj->reduce),
    // then Slocb bf16 (scan1->scan3), then opart (outGEMM->reduce_out).
    char* base = (char*)d_ws;
    unsigned short* xz_b    = (unsigned short*)(base + 0);         // 16.78MB bf16 proj|gate
    unsigned short* hid_b   = (unsigned short*)(base + 16777216);  // pre-GEMM1 only
    unsigned short* Win_b   = (unsigned short*)(base + 20971520);  // pre-GEMM1 only (ends 37748736)
    unsigned short* u_b     = (unsigned short*)(base + 16777216);  // 8.39MB (xproj_fused onward)
    float*          part16  = (float*)(base + 25165824);           // 16.78MB split-K partials
    unsigned short* Slocb   = (unsigned short*)(base + 25165824);  // 8.39MB bf16 (aliases part16)
    float*          opart   = (float*)(base + 25165824);           // 16.78MB (aliases Slocb)
    unsigned short* dlt_b   = (unsigned short*)(base + 41943040);  // 8.39MB
    unsigned short* y_b     = (unsigned short*)(base + 50331648);  // 8.39MB
    float*          projt   = (float*)(base + 58720256);           // 1.05MB (2048 x 128)
    unsigned short* Wout_b  = (unsigned short*)(base + 60293120);  // 4.19MB
    unsigned short* Wx_b    = (unsigned short*)(base + 64487424);  // 0.52MB (128 x 2048)
    unsigned short* Wdt_b   = (unsigned short*)(base + 65011712);  // 0.26MB
    float*          sumd    = (float*)(base + 65273856);           // 1.05MB (128 x 2048)

    // 0. all bf16 conversions in one dispatch (1097728 8-elem units)
    cvt_all<<<4289, 256, 0, stream>>>(hidden, W_in, W_out, W_dt, W_x,
                                      hid_b, Win_b, Wout_b, Wdt_b, Wx_b);

    // 1. xz = hidden @ W_in^T  (2048 x 4096, K=1024) bf16 MFMA -> bf16 out
    gemm_bf16<128, 128, 1><<<dim3(32, 16, 1), 256, 0, stream>>>(
        hid_b, DMODEL, Win_b, DMODEL, xz_b, 4096, 0, DMODEL, DMODEL);

    // 2+3. fused conv+silu + x-proj GEMM (split-K 16; also emits u_b)
    xproj_fused<<<dim3(1, 16, KSPLIT), 256, 0, stream>>>(
        xz_b, conv_w, conv_b, Wx_b, u_b, part16);

    // 4. fused split-K reduce + delta GEMM -> projt (fp32) + dlt_b (bf16)
    reduce_delta<<<NCH, 256, 0, stream>>>(part16, Wdt_b, dt_bias, projt, dlt_b);

    // 5-7. chunked selective scan (CHUNK=16, bf16 state) + fused epilogue
    scan_phase1<<<dim3(INNER / 256, NCH), 256, 0, stream>>>(
        dlt_b, u_b, projt, A_log, Slocb, sumd);
    scan_phase2<<<(INNER * DSTATE) / 64, 64, 0, stream>>>(Slocb, sumd, A_log);
    scan_phase3<<<dim3(INNER / 256, NCH), 256, 0, stream>>>(
        dlt_b, u_b, projt, A_log, Slocb, xz_b, D_skip, y_b);

    // 8. out = y @ W_out^T  (2048 x 1024, K=2048) bf16 MFMA, split-K 2 + combine
    gemm_bf16<128, 64, 0><<<dim3(16, 16, 2), 256, 0, stream>>>(
        y_b, INNER, Wout_b, INNER, opart, DMODEL, (long long)SEQLEN * DMODEL,
        INNER, INNER / 2);
    reduce_out<<<SEQLEN * DMODEL / 1024, 256, 0, stream>>>(opart, out);
}

// Round 12
// 161.298 us; speedup vs baseline: 1.1978x; 1.1978x over previous
//
#include <hip/hip_runtime.h>
#include <hip/hip_bf16.h>

#define SEQLEN 2048
#define DMODEL 1024
#define INNER  2048
#define DSTATE 16
#define DTRANK 64
#define NPROJ  96    // valid rows of W_x; padded to 128
#define NPAD   128
#define CHUNK  16
#define NCH    128   // SEQLEN / CHUNK
#define KSPLIT 16    // x-proj split-K ways

typedef __attribute__((ext_vector_type(8))) short bf16x8;
typedef __attribute__((ext_vector_type(4))) float f32x4;

__device__ __forceinline__ float softplusf(float x) {
    return (x > 20.f) ? x : log1pf(__expf(x));
}
__device__ __forceinline__ unsigned short f2bf(float x) {
    unsigned u = __float_as_uint(x);
    return (unsigned short)((u + 0x7FFF + ((u >> 16) & 1)) >> 16);
}
__device__ __forceinline__ float bf2f(unsigned short x) {
    return __uint_as_float((unsigned)x << 16);
}
__device__ __forceinline__ void gload_lds16(const void* g, void* l) {
    __builtin_amdgcn_global_load_lds(
        (__attribute__((address_space(1))) const unsigned int*)g,
        (__attribute__((address_space(3))) unsigned int*)l,
        16, 0, 0);
}
__device__ __forceinline__ void cvt8(const float* __restrict__ in,
                                     unsigned short* __restrict__ out, int i) {
    float4 a = ((const float4*)in)[2 * i];
    float4 b = ((const float4*)in)[2 * i + 1];
    uint4 v;
    v.x = f2bf(a.x) | ((unsigned)f2bf(a.y) << 16);
    v.y = f2bf(a.z) | ((unsigned)f2bf(a.w) << 16);
    v.z = f2bf(b.x) | ((unsigned)f2bf(b.y) << 16);
    v.w = f2bf(b.z) | ((unsigned)f2bf(b.w) << 16);
    ((uint4*)out)[i] = v;
}

// One-shot conversion of all bf16 operands.
// Segments (8-elem units): hidden 262144 | W_in 524288 | W_out 262144 |
// W_dt 16384 | W_x padded 96->128 rows 32768.  Total 1097728 units.
__global__ __launch_bounds__(256)
void cvt_all(const float* __restrict__ hidden, const float* __restrict__ W_in,
             const float* __restrict__ W_out, const float* __restrict__ W_dt,
             const float* __restrict__ W_x,
             unsigned short* __restrict__ hid_b, unsigned short* __restrict__ Win_b,
             unsigned short* __restrict__ Wout_b, unsigned short* __restrict__ Wdt_b,
             unsigned short* __restrict__ Wx_b)
{
    int i = blockIdx.x * 256 + threadIdx.x;
    if (i < 262144) { cvt8(hidden, hid_b, i); return; }
    i -= 262144;
    if (i < 524288) { cvt8(W_in, Win_b, i); return; }
    i -= 524288;
    if (i < 262144) { cvt8(W_out, Wout_b, i); return; }
    i -= 262144;
    if (i < 16384)  { cvt8(W_dt, Wdt_b, i); return; }
    i -= 16384;
    if (i < 32768) {
        int row = i >> 8;              // 256 units per 2048-wide row
        if (row < NPROJ) cvt8(W_x, Wx_b, i);
        else ((uint4*)Wx_b)[i] = make_uint4(0, 0, 0, 0);
    }
}

// C = A @ B^T, bf16 MFMA, fp32 accum.  BK=64, involution LDS swizzle
// (linear gload_lds dest + chunk^(row&7) pre-swizzled global source + XOR'd
// ds_read), bijective XCD swizzle on (bx,by).  Requires gridDim.x*y % 8 == 0,
// K/kspan % 64 == 0, M % BM == 0, N % BN == 0.
// 256 thr = 4 waves 2x2; wave tile (BM/2)x(BN/2); 16x16x32 MFMA.
// EPI 0: fp32 C (+ blockIdx.z*zCstride for split-K partials).
// EPI 1: bf16 C.  EPI 2: bf16 C = softplus(acc + bias[col]).
template<int BM, int BN, int EPI>
__global__ __launch_bounds__(256)
void gemm_bf16(const unsigned short* __restrict__ A, const int lda,
               const unsigned short* __restrict__ B, const int ldb,
               void* __restrict__ Cv, const int ldc, const long long zCstride,
               const int K, const int kspan, const float* __restrict__ bias)
{
    constexpr int FM = BM / 32;
    constexpr int FN = BN / 32;
    __shared__ alignas(16) short As[BM * 64];
    __shared__ alignas(16) short Bs[BN * 64];

    const int tid  = threadIdx.x;
    const int wave = tid >> 6;
    const int lane = tid & 63;

    // XCD-aware bijective swizzle of the flattened (bx,by) index
    int bid = blockIdx.y * gridDim.x + blockIdx.x;
    const int q = (gridDim.x * gridDim.y) >> 3;
    bid = (bid & 7) * q + (bid >> 3);
    const int bx = bid % gridDim.x;
    const int by = bid / gridDim.x;

    const long long row0 = (long long)by * BM;
    const long long col0 = (long long)bx * BN;
    const int wm = (wave >> 1) * (BM / 2);
    const int wn = (wave & 1) * (BN / 2);
    const int kstart = blockIdx.z * kspan;
    const int kend   = min(K, kstart + kspan);

    f32x4 acc[FM][FN] = {};

    // staging: thread t -> LDS row t/8 (+32 per pass), chunk t&7 (linear,
    // byte addr = t*16), fetching GLOBAL chunk (t&7)^(row&7)
    const int srow   = tid >> 3;
    const int schunk = (tid & 7) ^ (srow & 7);
    const unsigned short* gA = A + (row0 + srow) * lda + schunk * 8;
    const unsigned short* gB = B + (col0 + srow) * ldb + schunk * 8;
    short* lA = &As[srow * 64 + (tid & 7) * 8];
    short* lB = &Bs[srow * 64 + (tid & 7) * 8];

    const int fr = lane & 15;
    const int hi = lane >> 4;
    const int rb = fr & 7;            // row&7 of every fragment row this lane reads

    for (int kt = kstart; kt < kend; kt += 64) {
#pragma unroll
        for (int r = 0; r < BM; r += 32)
            gload_lds16(gA + (long long)r * lda + kt, lA + r * 64);
#pragma unroll
        for (int r = 0; r < BN; r += 32)
            gload_lds16(gB + (long long)r * ldb + kt, lB + r * 64);
        __syncthreads();

#pragma unroll
        for (int half = 0; half < 2; ++half) {
            const int kc = (((half << 2) + hi) ^ rb) * 8;   // swizzled 16B chunk
            bf16x8 af[FM], bfr[FN];
#pragma unroll
            for (int mi = 0; mi < FM; ++mi)
                af[mi] = *(const bf16x8*)&As[(wm + mi * 16 + fr) * 64 + kc];
#pragma unroll
            for (int ni = 0; ni < FN; ++ni)
                bfr[ni] = *(const bf16x8*)&Bs[(wn + ni * 16 + fr) * 64 + kc];
#pragma unroll
            for (int mi = 0; mi < FM; ++mi)
#pragma unroll
                for (int ni = 0; ni < FN; ++ni)
                    acc[mi][ni] = __builtin_amdgcn_mfma_f32_16x16x32_bf16(
                        af[mi], bfr[ni], acc[mi][ni], 0, 0, 0);
        }
        __syncthreads();
    }

    const int cr = hi * 4;            // C/D: col=lane&15, row=(lane>>4)*4+reg
#pragma unroll
    for (int mi = 0; mi < FM; ++mi)
#pragma unroll
        for (int ni = 0; ni < FN; ++ni) {
            long long rbase = row0 + wm + mi * 16 + cr;
            long long col   = col0 + wn + ni * 16 + fr;
#pragma unroll
            for (int r = 0; r < 4; ++r) {
                long long idx = (rbase + r) * ldc + col;
                if (EPI == 0) {
                    ((float*)Cv)[(long long)blockIdx.z * zCstride + idx] = acc[mi][ni][r];
                } else if (EPI == 1) {
                    ((unsigned short*)Cv)[idx] = f2bf(acc[mi][ni][r]);
                } else {
                    ((unsigned short*)Cv)[idx] = f2bf(softplusf(acc[mi][ni][r] + bias[col]));
                }
            }
        }
}

// Fused conv+silu+x-proj GEMM: part[z] = u_patch @ Wx^T where
// u = silu(depthwise_conv(xz_proj) + cb) is computed IN the A-staging from
// xz_b and also written to u_b (each (l,d) exactly once: z partitions the
// channel/K dim, by partitions rows).  BM=BN=128, BK=64, kspan=128,
// grid (1,16,KSPLIT); same swizzles/epilogue as gemm_bf16 EPI=0.
__global__ __launch_bounds__(256)
void xproj_fused(const unsigned short* __restrict__ xz_b,
                 const float* __restrict__ cw, const float* __restrict__ cb,
                 const unsigned short* __restrict__ Wx_b,
                 unsigned short* __restrict__ u_b, float* __restrict__ Cv)
{
    __shared__ alignas(16) short As[128 * 64];
    __shared__ alignas(16) short Bs[128 * 64];

    const int tid  = threadIdx.x;
    const int wave = tid >> 6;
    const int lane = tid & 63;

    int bid = blockIdx.y;                  // gridDim.x == 1, 16 blocks in y
    bid = (bid & 7) * 2 + (bid >> 3);      // bijective XCD swizzle (q=2)
    const long long row0 = (long long)bid * 128;

    const int wm = (wave >> 1) * 64;
    const int wn = (wave & 1) * 64;
    const int kstart = blockIdx.z * (INNER / KSPLIT);   // 128-channel span

    f32x4 acc[2][2] = {};

    const int srow   = tid >> 3;
    const int gchunk = (tid & 7) ^ (srow & 7);
    short* lA = &As[srow * 64 + (tid & 7) * 8];
    short* lB = &Bs[srow * 64 + (tid & 7) * 8];
    const unsigned short* gB = Wx_b + srow * INNER + gchunk * 8;

    const int fr = lane & 15;
    const int hi = lane >> 4;
    const int rb = fr & 7;

    for (int kt = kstart; kt < kstart + 128; kt += 64) {
        const int d = kt + gchunk * 8;     // my 8 channels this K-tile
        float4 wv[8];
#pragma unroll
        for (int k = 0; k < 8; ++k) wv[k] = ((const float4*)cw)[d + k];
        float bias8[8];
        {
            float4 c0 = ((const float4*)cb)[d >> 2];
            float4 c1 = ((const float4*)cb)[(d >> 2) + 1];
            bias8[0] = c0.x; bias8[1] = c0.y; bias8[2] = c0.z; bias8[3] = c0.w;
            bias8[4] = c1.x; bias8[5] = c1.y; bias8[6] = c1.z; bias8[7] = c1.w;
        }
#pragma unroll
        for (int r = 0; r < 128; r += 32) {
            const long long l = row0 + srow + r;
            float a[8];
#pragma unroll
            for (int k = 0; k < 8; ++k) a[k] = bias8[k];
#pragma unroll
            for (int j = 0; j < 4; ++j) {
                long long ls = l - 3 + j;
                if (ls >= 0) {
                    bf16x8 x = *(const bf16x8*)&xz_b[ls * 4096 + d];
#pragma unroll
                    for (int k = 0; k < 8; ++k)
                        a[k] = fmaf(((const float*)&wv[k])[j],
                                    bf2f((unsigned short)x[k]), a[k]);
                }
            }
            float s8[8];
#pragma unroll
            for (int k = 0; k < 8; ++k) s8[k] = a[k] / (1.f + __expf(-a[k]));
            uint4 p;
            p.x = f2bf(s8[0]) | ((unsigned)f2bf(s8[1]) << 16);
            p.y = f2bf(s8[2]) | ((unsigned)f2bf(s8[3]) << 16);
            p.z = f2bf(s8[4]) | ((unsigned)f2bf(s8[5]) << 16);
            p.w = f2bf(s8[6]) | ((unsigned)f2bf(s8[7]) << 16);
            *(uint4*)(lA + r * 64) = p;                 // swizzled LDS slot
            *(uint4*)&u_b[l * INNER + d] = p;           // global u (once)
        }
#pragma unroll
        for (int r = 0; r < 128; r += 32)
            gload_lds16(gB + (long long)r * INNER + kt, lB + r * 64);
        __syncthreads();

#pragma unroll
        for (int half = 0; half < 2; ++half) {
            const int kc = (((half << 2) + hi) ^ rb) * 8;
            bf16x8 af[2], bfr[2];
#pragma unroll
            for (int mi = 0; mi < 2; ++mi)
                af[mi] = *(const bf16x8*)&As[(wm + mi * 16 + fr) * 64 + kc];
#pragma unroll
            for (int ni = 0; ni < 2; ++ni)
                bfr[ni] = *(const bf16x8*)&Bs[(wn + ni * 16 + fr) * 64 + kc];
#pragma unroll
            for (int mi = 0; mi < 2; ++mi)
#pragma unroll
                for (int ni = 0; ni < 2; ++ni)
                    acc[mi][ni] = __builtin_amdgcn_mfma_f32_16x16x32_bf16(
                        af[mi], bfr[ni], acc[mi][ni], 0, 0, 0);
        }
        __syncthreads();
    }

    const int cr = hi * 4;
#pragma unroll
    for (int mi = 0; mi < 2; ++mi)
#pragma unroll
        for (int ni = 0; ni < 2; ++ni) {
            long long rbase = row0 + wm + mi * 16 + cr;
            long long col   = wn + ni * 16 + fr;
#pragma unroll
            for (int r = 0; r < 4; ++r)
                Cv[(long long)blockIdx.z * (SEQLEN * NPAD) +
                   (rbase + r) * NPAD + col] = acc[mi][ni][r];
        }
}

// out[i] = p0[i] + p1[i]  (split-K=2 combine), float4 vectorized
__global__ __launch_bounds__(256)
void reduce_out(const float* __restrict__ part, float* __restrict__ out)
{
    int i = blockIdx.x * 256 + threadIdx.x;   // i < SEQLEN*DMODEL/4
    float4 a = ((const float4*)part)[i];
    float4 b = ((const float4*)part)[i + SEQLEN * DMODEL / 4];
    a.x += b.x; a.y += b.y; a.z += b.z; a.w += b.w;
    ((float4*)out)[i] = a;
}

// projt[i] = sum_z part[z][i]; emits fp32 projt and bf16 projt_b (i < 2048*128)
__global__ __launch_bounds__(256)
void reduce_part(const float* __restrict__ part, float* __restrict__ projt,
                 unsigned short* __restrict__ projt_b)
{
    int i = blockIdx.x * 256 + threadIdx.x;
    float s = 0.f;
#pragma unroll
    for (int z = 0; z < KSPLIT; ++z) s += part[(long long)z * SEQLEN * NPAD + i];
    projt[i] = s;
    projt_b[i] = f2bf(s);
}

// Phase 1: local chunk scans (h0=0) -> bf16 chunk-final states + delta sums
__global__ __launch_bounds__(256)
void scan_phase1(const unsigned short* __restrict__ delta_bf,
                 const unsigned short* __restrict__ u_b,
                 const float* __restrict__ projt, const float* __restrict__ A_log,
                 unsigned short* __restrict__ Slocb, float* __restrict__ sumd)
{
    __shared__ float Bsh[CHUNK][16];
    const int d  = blockIdx.x * 256 + threadIdx.x;
    const int c  = blockIdx.y;
    const int l0 = c * CHUNK;
    for (int i = threadIdx.x; i < CHUNK * 16; i += 256) {
        int l = i >> 4, j = i & 15;
        Bsh[l][j] = projt[(l0 + l) * NPAD + DTRANK + j];
    }
    __syncthreads();

    float A2[DSTATE];
#pragma unroll
    for (int n = 0; n < DSTATE; ++n)
        A2[n] = -__expf(A_log[d * DSTATE + n]) * 1.4426950408889634f;

    float dl[CHUNK], du[CHUNK];
#pragma unroll
    for (int t = 0; t < CHUNK; ++t) {
        int l = l0 + t;
        float dv = bf2f(delta_bf[l * INNER + d]);
        dl[t] = dv;
        du[t] = dv * bf2f(u_b[l * INNER + d]);
    }

    float h[DSTATE];
#pragma unroll
    for (int n = 0; n < DSTATE; ++n) h[n] = 0.f;
    float sd = 0.f;

#pragma unroll
    for (int t = 0; t < CHUNK; ++t) {
        sd += dl[t];
#pragma unroll
        for (int n = 0; n < DSTATE; ++n) {
            float dA = exp2f(dl[t] * A2[n]);
            h[n] = fmaf(dA, h[n], du[t] * Bsh[t][n]);
        }
    }
    uint4 p0, p1;
    p0.x = f2bf(h[0])  | ((unsigned)f2bf(h[1])  << 16);
    p0.y = f2bf(h[2])  | ((unsigned)f2bf(h[3])  << 16);
    p0.z = f2bf(h[4])  | ((unsigned)f2bf(h[5])  << 16);
    p0.w = f2bf(h[6])  | ((unsigned)f2bf(h[7])  << 16);
    p1.x = f2bf(h[8])  | ((unsigned)f2bf(h[9])  << 16);
    p1.y = f2bf(h[10]) | ((unsigned)f2bf(h[11]) << 16);
    p1.z = f2bf(h[12]) | ((unsigned)f2bf(h[13]) << 16);
    p1.w = f2bf(h[14]) | ((unsigned)f2bf(h[15]) << 16);
    uint4* dst = (uint4*)&Slocb[(long long)(c * INNER + d) * DSTATE];
    dst[0] = p0; dst[1] = p1;
    sumd[c * INNER + d] = sd;
}

// Phase 2 (in-place, bf16 state): S[c] chunk-final -> state at chunk start.
// 512 x 64-thread blocks: spread the serial-chain kernel over all 256 CUs.
__global__ __launch_bounds__(64)
void scan_phase2(unsigned short* __restrict__ S, const float* __restrict__ sumd,
                 const float* __restrict__ A_log)
{
    int i = blockIdx.x * 64 + threadIdx.x;   // i < INNER*DSTATE
    int d = i >> 4;
    float A2 = -__expf(A_log[i]) * 1.4426950408889634f;
    float H = 0.f;
#pragma unroll
    for (int c = 0; c < NCH; ++c) {
        float s = bf2f(S[c * (INNER * DSTATE) + i]);
        float P = exp2f(A2 * sumd[c * INNER + d]);
        S[c * (INNER * DSTATE) + i] = f2bf(H);
        H = fmaf(P, H, s);
    }
}

// Phase 3: re-scan from bf16 Hinit; y = (h.C + D*u) * silu(gate) -> bf16 y_b
__global__ __launch_bounds__(256)
void scan_phase3(const unsigned short* __restrict__ delta_bf,
                 const unsigned short* __restrict__ u_b,
                 const float* __restrict__ projt, const float* __restrict__ A_log,
                 const unsigned short* __restrict__ Hinit,
                 const unsigned short* __restrict__ xz_b,
                 const float* __restrict__ D_skip, unsigned short* __restrict__ ybf)
{
    __shared__ float BC[CHUNK][32];
    const int d  = blockIdx.x * 256 + threadIdx.x;
    const int c  = blockIdx.y;
    const int l0 = c * CHUNK;
    for (int i = threadIdx.x; i < CHUNK * 32; i += 256) {
        int l = i >> 5, j = i & 31;
        BC[l][j] = projt[(l0 + l) * NPAD + DTRANK + j];
    }
    __syncthreads();

    float A2[DSTATE];
#pragma unroll
    for (int n = 0; n < DSTATE; ++n)
        A2[n] = -__expf(A_log[d * DSTATE + n]) * 1.4426950408889634f;

    float dl[CHUNK], uv[CHUNK];
#pragma unroll
    for (int t = 0; t < CHUNK; ++t) {
        int l = l0 + t;
        dl[t] = bf2f(delta_bf[l * INNER + d]);
        uv[t] = bf2f(u_b[l * INNER + d]);
    }

    float h[DSTATE];
    {
        const uint4* hp = (const uint4*)&Hinit[(long long)(c * INNER + d) * DSTATE];
        uint4 p0 = hp[0], p1 = hp[1];
        h[0]  = bf2f((unsigned short)(p0.x & 0xffff)); h[1]  = bf2f((unsigned short)(p0.x >> 16));
        h[2]  = bf2f((unsigned short)(p0.y & 0xffff)); h[3]  = bf2f((unsigned short)(p0.y >> 16));
        h[4]  = bf2f((unsigned short)(p0.z & 0xffff)); h[5]  = bf2f((unsigned short)(p0.z >> 16));
        h[6]  = bf2f((unsigned short)(p0.w & 0xffff)); h[7]  = bf2f((unsigned short)(p0.w >> 16));
        h[8]  = bf2f((unsigned short)(p1.x & 0xffff)); h[9]  = bf2f((unsigned short)(p1.x >> 16));
        h[10] = bf2f((unsigned short)(p1.y & 0xffff)); h[11] = bf2f((unsigned short)(p1.y >> 16));
        h[12] = bf2f((unsigned short)(p1.z & 0xffff)); h[13] = bf2f((unsigned short)(p1.z >> 16));
        h[14] = bf2f((unsigned short)(p1.w & 0xffff)); h[15] = bf2f((unsigned short)(p1.w >> 16));
    }
    const float Dd = D_skip[d];

#pragma unroll
    for (int t = 0; t < CHUNK; ++t) {
        int l = l0 + t;
        float du = dl[t] * uv[t];
        float y = 0.f;
#pragma unroll
        for (int n = 0; n < DSTATE; ++n) {
            float dA = exp2f(dl[t] * A2[n]);
            h[n] = fmaf(dA, h[n], du * BC[t][n]);
            y = fmaf(h[n], BC[t][16 + n], y);
        }
        float yv = fmaf(Dd, uv[t], y);
        float g = bf2f(xz_b[(long long)l * 4096 + 2048 + d]);
        float sg = g / (1.f + __expf(-g));
        ybf[l * INNER + d] = f2bf(yv * sg);
    }
}

extern "C" void kernel_launch(void* const* d_in, const int* in_sizes, int n_in,
                              void* d_out, int out_size, void* d_ws, size_t ws_size,
                              hipStream_t stream)
{
    const float* hidden  = (const float*)d_in[0];
    const float* W_in    = (const float*)d_in[1];
    const float* conv_w  = (const float*)d_in[2];
    const float* conv_b  = (const float*)d_in[3];
    const float* W_x     = (const float*)d_in[4];
    const float* W_dt    = (const float*)d_in[5];
    const float* dt_bias = (const float*)d_in[6];
    const float* A_log   = (const float*)d_in[7];
    const float* D_skip  = (const float*)d_in[8];
    const float* W_out   = (const float*)d_in[9];
    float* out = (float*)d_out;

    // workspace layout, 66.3 MB total (proven ceiling 82.6 MB, round 4).
    // Triple-aliased slot [25165824, 41943040): part16 (xproj->reduce),
    // then Slocb bf16 (scan1->scan3), then opart (outGEMM->reduce_out).
    char* base = (char*)d_ws;
    unsigned short* xz_b    = (unsigned short*)(base + 0);         // 16.78MB bf16 proj|gate
    unsigned short* hid_b   = (unsigned short*)(base + 16777216);  // pre-GEMM1 only
    unsigned short* Win_b   = (unsigned short*)(base + 20971520);  // pre-GEMM1 only (ends 37748736)
    unsigned short* u_b     = (unsigned short*)(base + 16777216);  // 8.39MB (xproj_fused onward)
    float*          part16  = (float*)(base + 25165824);           // 16.78MB split-K partials
    unsigned short* Slocb   = (unsigned short*)(base + 25165824);  // 8.39MB bf16 (aliases part16)
    float*          opart   = (float*)(base + 25165824);           // 16.78MB (aliases Slocb)
    unsigned short* dlt_b   = (unsigned short*)(base + 41943040);  // 8.39MB
    unsigned short* y_b     = (unsigned short*)(base + 50331648);  // 8.39MB
    float*          projt   = (float*)(base + 58720256);           // 1.05MB (2048 x 128)
    unsigned short* projt_b = (unsigned short*)(base + 59768832);  // 0.52MB
    unsigned short* Wout_b  = (unsigned short*)(base + 60293120);  // 4.19MB
    unsigned short* Wx_b    = (unsigned short*)(base + 64487424);  // 0.52MB (128 x 2048)
    unsigned short* Wdt_b   = (unsigned short*)(base + 65011712);  // 0.26MB
    float*          sumd    = (float*)(base + 65273856);           // 1.05MB (128 x 2048)

    // 0. all bf16 conversions in one dispatch (1097728 8-elem units)
    cvt_all<<<4289, 256, 0, stream>>>(hidden, W_in, W_out, W_dt, W_x,
                                      hid_b, Win_b, Wout_b, Wdt_b, Wx_b);

    // 1. xz = hidden @ W_in^T  (2048 x 4096, K=1024) bf16 MFMA -> bf16 out
    gemm_bf16<128, 128, 1><<<dim3(32, 16, 1), 256, 0, stream>>>(
        hid_b, DMODEL, Win_b, DMODEL, xz_b, 4096, 0, DMODEL, DMODEL, nullptr);

    // 2+3. fused conv+silu + x-proj GEMM (split-K 16; also emits u_b), + reduce
    xproj_fused<<<dim3(1, 16, KSPLIT), 256, 0, stream>>>(
        xz_b, conv_w, conv_b, Wx_b, u_b, part16);
    reduce_part<<<SEQLEN * NPAD / 256, 256, 0, stream>>>(part16, projt, projt_b);

    // 4. delta = softplus(dt_lr @ W_dt^T + dt_bias) -> bf16  (2048 x 2048, K=64)
    gemm_bf16<128, 64, 2><<<dim3(32, 16, 1), 256, 0, stream>>>(
        projt_b, NPAD, Wdt_b, DTRANK, dlt_b, INNER, 0, DTRANK, DTRANK, dt_bias);

    // 5-7. chunked selective scan (CHUNK=16, bf16 state) + fused epilogue
    scan_phase1<<<dim3(INNER / 256, NCH), 256, 0, stream>>>(
        dlt_b, u_b, projt, A_log, Slocb, sumd);
    scan_phase2<<<(INNER * DSTATE) / 64, 64, 0, stream>>>(Slocb, sumd, A_log);
    scan_phase3<<<dim3(INNER / 256, NCH), 256, 0, stream>>>(
        dlt_b, u_b, projt, A_log, Slocb, xz_b, D_skip, y_b);

    // 8. out = y @ W_out^T  (2048 x 1024, K=2048) bf16 MFMA, split-K 2 + combine
    gemm_bf16<128, 64, 0><<<dim3(16, 16, 2), 256, 0, stream>>>(
        y_b, INNER, Wout_b, INNER, opart, DMODEL, (long long)SEQLEN * DMODEL,
        INNER, INNER / 2, nullptr);
    reduce_out<<<SEQLEN * DMODEL / 1024, 256, 0, stream>>>(opart, out);
}